// Round 8
// baseline (970.996 us; speedup 1.0000x reference)
//
#include <hip/hip_runtime.h>
#include <stdint.h>
#include <stddef.h>

// ScaledDotProductAttention: B=64, Lq=Lk=2048, D=64, fp32 in/out.
// out tuple = (output [64][2048][64], attn [64][2048][2048]) concat in d_out.
// R8: R5 structure but ZERO private arrays — 32 named f16x4 logit registers,
// named K/mask/V pipeline slots, all phases macro-expanded. Rationale: R3-R7
// all had VGPR_Count 80-116 (< live state), i.e. the compiler put ph[] in
// scratch (rule #20: partially-unrolled loop -> runtime index -> localMem),
// adding ~1KB/lane scratch round-trips on the critical path (~5x penalty).

typedef __attribute__((ext_vector_type(4))) float f32x4;
typedef __fp16 f16x2 __attribute__((ext_vector_type(2)));
typedef __fp16 f16x4 __attribute__((ext_vector_type(4)));
typedef __fp16 f16x8 __attribute__((ext_vector_type(8)));

static constexpr int BATCH = 64;
static constexpr int SEQ   = 2048;   // lq == lk
static constexpr int HD    = 64;     // head dim
static constexpr float NEGH = -60000.0f;  // "-inf" that survives fp16

// ---------------- pre-pass: fp32 -> fp16 flat convert ----------------
__global__ void cvt_f16_kernel(const float* __restrict__ in,
                               __fp16* __restrict__ out, int n4) {
  int i = blockIdx.x * blockDim.x + threadIdx.x;
  if (i >= n4) return;
  f32x4 v = *(const f32x4*)(in + (size_t)i * 4);
  f16x4 o;
  o[0] = (__fp16)v[0]; o[1] = (__fp16)v[1];
  o[2] = (__fp16)v[2]; o[3] = (__fp16)v[3];
  *(f16x4*)(out + (size_t)i * 4) = o;
}

// ---------------- pre-pass: V [b][k][d] fp32 -> VT fp16 [b][d][k] ----------
__global__ void vtrans_kernel(const float* __restrict__ v,
                              __fp16* __restrict__ vt) {
  __shared__ float tile[64][65];
  const int b  = blockIdx.x >> 5;
  const int k0 = (blockIdx.x & 31) << 6;
  const int t  = threadIdx.x;
  const int kk = t >> 4;
  const int d4 = (t & 15) << 2;
#pragma unroll
  for (int i = 0; i < 4; ++i) {
    f32x4 val = *(const f32x4*)(v + ((size_t)(b * SEQ + k0 + kk + 16 * i)) * HD + d4);
    tile[kk + 16 * i][d4 + 0] = val[0];
    tile[kk + 16 * i][d4 + 1] = val[1];
    tile[kk + 16 * i][d4 + 2] = val[2];
    tile[kk + 16 * i][d4 + 3] = val[3];
  }
  __syncthreads();
  const int d  = t >> 2;
  const int ks = (t & 3) << 4;
  f16x8 o0, o1;
#pragma unroll
  for (int j = 0; j < 8; ++j) o0[j] = (__fp16)tile[ks + j][d];
#pragma unroll
  for (int j = 0; j < 8; ++j) o1[j] = (__fp16)tile[ks + 8 + j][d];
  __fp16* dst = vt + ((size_t)(b * HD + d)) * SEQ + k0 + ks;
  *(f16x8*)(dst)     = o0;
  *(f16x8*)(dst + 8) = o1;
}

// ---------------- main fused attention ----------------
// grid: 64 batches x 128 q-tiles; block 256 (4 waves); wave w owns k-range
// [w*512, w*512+512). Lane (g,l15): q-row = l15, k = tile*16 + g*4 + {0..3}.
__global__ __launch_bounds__(256, 2) void attn_kernel(
    const __fp16* __restrict__ qh,
    const __fp16* __restrict__ kh,
    const __fp16* __restrict__ vth,
    const float* __restrict__ mask,
    float* __restrict__ out,
    float* __restrict__ attn) {
  __shared__ float s_red[4][64 * 17];   // O partials [wave][d][q(+pad)]
  __shared__ float stat_m[4][16];
  __shared__ float stat_l[4][16];

  const int tid  = threadIdx.x;
  const int w    = tid >> 6;
  const int lane = tid & 63;
  const int l15  = lane & 15;
  const int g    = lane >> 4;   // 16-lane group 0..3
  const int g4   = g << 2;
  const int g8   = g << 3;

  const int b   = blockIdx.x >> 7;
  const int q0  = (blockIdx.x & 127) << 4;
  const int wk0 = w << 9;

  // Q = B operand (col=l15 -> q-row, k=g*8+j -> head-dim)
  const __fp16* qptr = qh + ((size_t)(b * SEQ + q0 + l15)) * HD;
  const f16x8 qb0 = *(const f16x8*)(qptr + g8);
  const f16x8 qb1 = *(const f16x8*)(qptr + 32 + g8);

  // K = A operand (row=l15 -> k-row within tile, k=g*8+j -> head-dim)
  const __fp16* kbase = kh + ((size_t)(b * SEQ + wk0 + l15)) * HD;
  const float*  mptr  = mask + ((size_t)(b * SEQ) + q0 + l15) * (size_t)SEQ + wk0 + g4;

  // 32 named logit fragments (f16x4 = 2 VGPR each, 64 VGPRs total)
  f16x4 PH0,  PH1,  PH2,  PH3,  PH4,  PH5,  PH6,  PH7;
  f16x4 PH8,  PH9,  PH10, PH11, PH12, PH13, PH14, PH15;
  f16x4 PH16, PH17, PH18, PH19, PH20, PH21, PH22, PH23;
  f16x4 PH24, PH25, PH26, PH27, PH28, PH29, PH30, PH31;

  // named pipeline slots
  f16x8 KAe0, KAe1, KAo0, KAo1;   // K: 2-deep (even/odd)
  f32x4 MB0, MB1, MB2, MB3;       // mask: 4-deep
  float m = -3.0e38f;

  // prologue
  KAe0 = *(const f16x8*)(kbase + g8);
  KAe1 = *(const f16x8*)(kbase + 32 + g8);
  KAo0 = *(const f16x8*)(kbase + 16 * HD + g8);
  KAo1 = *(const f16x8*)(kbase + 16 * HD + 32 + g8);
  MB0 = __builtin_nontemporal_load((const f32x4*)(mptr + 0 * 16));
  MB1 = __builtin_nontemporal_load((const f32x4*)(mptr + 1 * 16));
  MB2 = __builtin_nontemporal_load((const f32x4*)(mptr + 2 * 16));
  MB3 = __builtin_nontemporal_load((const f32x4*)(mptr + 3 * 16));

#define A_STEP(T, PH, KA0, KA1, MB)                                          \
  {                                                                          \
    f32x4 acc = {0.f, 0.f, 0.f, 0.f};                                        \
    acc = __builtin_amdgcn_mfma_f32_16x16x32_f16(KA0, qb0, acc, 0, 0, 0);    \
    acc = __builtin_amdgcn_mfma_f32_16x16x32_f16(KA1, qb1, acc, 0, 0, 0);    \
    const f32x4 mv = MB;                                                     \
    if ((T) + 2 < 32) {                                                      \
      const __fp16* kp = kbase + (size_t)((T) + 2) * (16 * HD);              \
      KA0 = *(const f16x8*)(kp + g8);                                        \
      KA1 = *(const f16x8*)(kp + 32 + g8);                                   \
    }                                                                        \
    if ((T) + 4 < 32)                                                        \
      MB = __builtin_nontemporal_load((const f32x4*)(mptr + ((T) + 4) * 16));\
    float s0 = (mv[0] < 0.f) ? NEGH : fmaf(acc[0], 0.125f, mv[0]);           \
    float s1 = (mv[1] < 0.f) ? NEGH : fmaf(acc[1], 0.125f, mv[1]);           \
    float s2 = (mv[2] < 0.f) ? NEGH : fmaf(acc[2], 0.125f, mv[2]);           \
    float s3 = (mv[3] < 0.f) ? NEGH : fmaf(acc[3], 0.125f, mv[3]);           \
    m = fmaxf(m, fmaxf(fmaxf(s0, s1), fmaxf(s2, s3)));                       \
    f16x2 lo = __builtin_amdgcn_cvt_pkrtz(s0, s1);                           \
    f16x2 hi = __builtin_amdgcn_cvt_pkrtz(s2, s3);                           \
    PH = (f16x4){lo[0], lo[1], hi[0], hi[1]};                                \
  }

  A_STEP(0,  PH0,  KAe0, KAe1, MB0)  A_STEP(1,  PH1,  KAo0, KAo1, MB1)
  A_STEP(2,  PH2,  KAe0, KAe1, MB2)  A_STEP(3,  PH3,  KAo0, KAo1, MB3)
  A_STEP(4,  PH4,  KAe0, KAe1, MB0)  A_STEP(5,  PH5,  KAo0, KAo1, MB1)
  A_STEP(6,  PH6,  KAe0, KAe1, MB2)  A_STEP(7,  PH7,  KAo0, KAo1, MB3)
  A_STEP(8,  PH8,  KAe0, KAe1, MB0)  A_STEP(9,  PH9,  KAo0, KAo1, MB1)
  A_STEP(10, PH10, KAe0, KAe1, MB2)  A_STEP(11, PH11, KAo0, KAo1, MB3)
  A_STEP(12, PH12, KAe0, KAe1, MB0)  A_STEP(13, PH13, KAo0, KAo1, MB1)
  A_STEP(14, PH14, KAe0, KAe1, MB2)  A_STEP(15, PH15, KAo0, KAo1, MB3)
  A_STEP(16, PH16, KAe0, KAe1, MB0)  A_STEP(17, PH17, KAo0, KAo1, MB1)
  A_STEP(18, PH18, KAe0, KAe1, MB2)  A_STEP(19, PH19, KAo0, KAo1, MB3)
  A_STEP(20, PH20, KAe0, KAe1, MB0)  A_STEP(21, PH21, KAo0, KAo1, MB1)
  A_STEP(22, PH22, KAe0, KAe1, MB2)  A_STEP(23, PH23, KAo0, KAo1, MB3)
  A_STEP(24, PH24, KAe0, KAe1, MB0)  A_STEP(25, PH25, KAo0, KAo1, MB1)
  A_STEP(26, PH26, KAe0, KAe1, MB2)  A_STEP(27, PH27, KAo0, KAo1, MB3)
  A_STEP(28, PH28, KAe0, KAe1, MB0)  A_STEP(29, PH29, KAo0, KAo1, MB1)
  A_STEP(30, PH30, KAe0, KAe1, MB2)  A_STEP(31, PH31, KAo0, KAo1, MB3)
#undef A_STEP

  // row max across the 4 g-groups holding the same q-row
  m = fmaxf(m, __shfl_xor(m, 16));
  m = fmaxf(m, __shfl_xor(m, 32));

  // ---- Phase A2: e = exp(s - m), sum, repack e over s ----
  float lw = 0.f;
#define A2_STEP(PH)                                                          \
  {                                                                          \
    float e0 = __expf((float)PH[0] - m);                                     \
    float e1 = __expf((float)PH[1] - m);                                     \
    float e2 = __expf((float)PH[2] - m);                                     \
    float e3 = __expf((float)PH[3] - m);                                     \
    lw += (e0 + e1) + (e2 + e3);                                             \
    f16x2 lo = __builtin_amdgcn_cvt_pkrtz(e0, e1);                           \
    f16x2 hi = __builtin_amdgcn_cvt_pkrtz(e2, e3);                           \
    PH = (f16x4){lo[0], lo[1], hi[0], hi[1]};                                \
  }
  A2_STEP(PH0)  A2_STEP(PH1)  A2_STEP(PH2)  A2_STEP(PH3)
  A2_STEP(PH4)  A2_STEP(PH5)  A2_STEP(PH6)  A2_STEP(PH7)
  A2_STEP(PH8)  A2_STEP(PH9)  A2_STEP(PH10) A2_STEP(PH11)
  A2_STEP(PH12) A2_STEP(PH13) A2_STEP(PH14) A2_STEP(PH15)
  A2_STEP(PH16) A2_STEP(PH17) A2_STEP(PH18) A2_STEP(PH19)
  A2_STEP(PH20) A2_STEP(PH21) A2_STEP(PH22) A2_STEP(PH23)
  A2_STEP(PH24) A2_STEP(PH25) A2_STEP(PH26) A2_STEP(PH27)
  A2_STEP(PH28) A2_STEP(PH29) A2_STEP(PH30) A2_STEP(PH31)
#undef A2_STEP

  lw += __shfl_xor(lw, 16);
  lw += __shfl_xor(lw, 32);

  if (lane < 16) { stat_m[w][lane] = m; stat_l[w][lane] = lw; }
  __syncthreads();

  float mg = -3.0e38f;
#pragma unroll
  for (int ww = 0; ww < 4; ++ww) mg = fmaxf(mg, stat_m[ww][l15]);
  float lg = 0.f;
#pragma unroll
  for (int ww = 0; ww < 4; ++ww) lg += stat_l[ww][l15] * __expf(stat_m[ww][l15] - mg);
  const float scale = __expf(m - mg) / lg;
  const __fp16 hs = (__fp16)scale;
  const f16x4 sc4 = {hs, hs, hs, hs};

  // ---- Phase B: attn stores (f32x4) + PV via 16x16x16 f16 MFMA ----
  f32x4 oacc0 = {0.f, 0.f, 0.f, 0.f};
  f32x4 oacc1 = {0.f, 0.f, 0.f, 0.f};
  f32x4 oacc2 = {0.f, 0.f, 0.f, 0.f};
  f32x4 oacc3 = {0.f, 0.f, 0.f, 0.f};

  float* attn_base = attn + ((size_t)(b * SEQ) + q0 + l15) * (size_t)SEQ + wk0 + g4;
  const __fp16* vbase = vth + ((size_t)(b * HD + l15)) * SEQ + wk0 + g4;

  // V pipeline: 2 named slot sets, 1-step lookahead (L2-resident)
  f16x4 VA0, VA1, VA2, VA3, VB0, VB1, VB2, VB3;
  VA0 = *(const f16x4*)(vbase + (size_t)(0 * 16) * SEQ);
  VA1 = *(const f16x4*)(vbase + (size_t)(1 * 16) * SEQ);
  VA2 = *(const f16x4*)(vbase + (size_t)(2 * 16) * SEQ);
  VA3 = *(const f16x4*)(vbase + (size_t)(3 * 16) * SEQ);

#define B_STEP(T, PH, U0, U1, U2, U3, N0, N1, N2, N3)                        \
  {                                                                          \
    if ((T) + 1 < 32) {                                                      \
      N0 = *(const f16x4*)(vbase + (size_t)(0 * 16) * SEQ + ((T) + 1) * 16); \
      N1 = *(const f16x4*)(vbase + (size_t)(1 * 16) * SEQ + ((T) + 1) * 16); \
      N2 = *(const f16x4*)(vbase + (size_t)(2 * 16) * SEQ + ((T) + 1) * 16); \
      N3 = *(const f16x4*)(vbase + (size_t)(3 * 16) * SEQ + ((T) + 1) * 16); \
    }                                                                        \
    const f16x4 pf = PH * sc4;                                               \
    f32x4 st;                                                                \
    st[0] = (float)pf[0]; st[1] = (float)pf[1];                              \
    st[2] = (float)pf[2]; st[3] = (float)pf[3];                              \
    __builtin_nontemporal_store(st, (f32x4*)(attn_base + (T) * 16));         \
    oacc0 = __builtin_amdgcn_mfma_f32_16x16x16f16(U0, pf, oacc0, 0, 0, 0);   \
    oacc1 = __builtin_amdgcn_mfma_f32_16x16x16f16(U1, pf, oacc1, 0, 0, 0);   \
    oacc2 = __builtin_amdgcn_mfma_f32_16x16x16f16(U2, pf, oacc2, 0, 0, 0);   \
    oacc3 = __builtin_amdgcn_mfma_f32_16x16x16f16(U3, pf, oacc3, 0, 0, 0);   \
  }

  B_STEP(0,  PH0,  VA0, VA1, VA2, VA3, VB0, VB1, VB2, VB3)
  B_STEP(1,  PH1,  VB0, VB1, VB2, VB3, VA0, VA1, VA2, VA3)
  B_STEP(2,  PH2,  VA0, VA1, VA2, VA3, VB0, VB1, VB2, VB3)
  B_STEP(3,  PH3,  VB0, VB1, VB2, VB3, VA0, VA1, VA2, VA3)
  B_STEP(4,  PH4,  VA0, VA1, VA2, VA3, VB0, VB1, VB2, VB3)
  B_STEP(5,  PH5,  VB0, VB1, VB2, VB3, VA0, VA1, VA2, VA3)
  B_STEP(6,  PH6,  VA0, VA1, VA2, VA3, VB0, VB1, VB2, VB3)
  B_STEP(7,  PH7,  VB0, VB1, VB2, VB3, VA0, VA1, VA2, VA3)
  B_STEP(8,  PH8,  VA0, VA1, VA2, VA3, VB0, VB1, VB2, VB3)
  B_STEP(9,  PH9,  VB0, VB1, VB2, VB3, VA0, VA1, VA2, VA3)
  B_STEP(10, PH10, VA0, VA1, VA2, VA3, VB0, VB1, VB2, VB3)
  B_STEP(11, PH11, VB0, VB1, VB2, VB3, VA0, VA1, VA2, VA3)
  B_STEP(12, PH12, VA0, VA1, VA2, VA3, VB0, VB1, VB2, VB3)
  B_STEP(13, PH13, VB0, VB1, VB2, VB3, VA0, VA1, VA2, VA3)
  B_STEP(14, PH14, VA0, VA1, VA2, VA3, VB0, VB1, VB2, VB3)
  B_STEP(15, PH15, VB0, VB1, VB2, VB3, VA0, VA1, VA2, VA3)
  B_STEP(16, PH16, VA0, VA1, VA2, VA3, VB0, VB1, VB2, VB3)
  B_STEP(17, PH17, VB0, VB1, VB2, VB3, VA0, VA1, VA2, VA3)
  B_STEP(18, PH18, VA0, VA1, VA2, VA3, VB0, VB1, VB2, VB3)
  B_STEP(19, PH19, VB0, VB1, VB2, VB3, VA0, VA1, VA2, VA3)
  B_STEP(20, PH20, VA0, VA1, VA2, VA3, VB0, VB1, VB2, VB3)
  B_STEP(21, PH21, VB0, VB1, VB2, VB3, VA0, VA1, VA2, VA3)
  B_STEP(22, PH22, VA0, VA1, VA2, VA3, VB0, VB1, VB2, VB3)
  B_STEP(23, PH23, VB0, VB1, VB2, VB3, VA0, VA1, VA2, VA3)
  B_STEP(24, PH24, VA0, VA1, VA2, VA3, VB0, VB1, VB2, VB3)
  B_STEP(25, PH25, VB0, VB1, VB2, VB3, VA0, VA1, VA2, VA3)
  B_STEP(26, PH26, VA0, VA1, VA2, VA3, VB0, VB1, VB2, VB3)
  B_STEP(27, PH27, VB0, VB1, VB2, VB3, VA0, VA1, VA2, VA3)
  B_STEP(28, PH28, VA0, VA1, VA2, VA3, VB0, VB1, VB2, VB3)
  B_STEP(29, PH29, VB0, VB1, VB2, VB3, VA0, VA1, VA2, VA3)
  B_STEP(30, PH30, VA0, VA1, VA2, VA3, VB0, VB1, VB2, VB3)
  B_STEP(31, PH31, VB0, VB1, VB2, VB3, VA0, VA1, VA2, VA3)
#undef B_STEP

  // ---- cross-wave partial-O reduction ----
  // oaccD[r] = O^T[d = D*16 + g*4 + r][q = l15] (partial over wave's k)
#pragma unroll
  for (int r = 0; r < 4; ++r) {
    s_red[w][(0 * 16 + g4 + r) * 17 + l15] = oacc0[r];
    s_red[w][(1 * 16 + g4 + r) * 17 + l15] = oacc1[r];
    s_red[w][(2 * 16 + g4 + r) * 17 + l15] = oacc2[r];
    s_red[w][(3 * 16 + g4 + r) * 17 + l15] = oacc3[r];
  }
  __syncthreads();

#pragma unroll
  for (int ii = 0; ii < 4; ++ii) {
    const int i = tid + ii * 256;     // i in [0,1024): q = i>>6, d = i&63
    const int q = i >> 6;
    const int d = i & 63;
    const int o = d * 17 + q;
    float s = s_red[0][o] + s_red[1][o] + s_red[2][o] + s_red[3][o];
    out[((size_t)(b * SEQ + q0 + q)) * HD + d] = s;
  }
}

extern "C" void kernel_launch(void* const* d_in, const int* in_sizes, int n_in,
                              void* d_out, int out_size, void* d_ws, size_t ws_size,
                              hipStream_t stream) {
  const float* q    = (const float*)d_in[0];
  const float* k    = (const float*)d_in[1];
  const float* v    = (const float*)d_in[2];
  const float* mask = (const float*)d_in[3];

  float* out  = (float*)d_out;
  float* attn = out + (size_t)BATCH * SEQ * HD;  // tuple: (output, attn)

  const size_t nqk = (size_t)BATCH * SEQ * HD;
  __fp16* qh = (__fp16*)d_ws;
  __fp16* kh = qh + nqk;
  __fp16* vt = kh + nqk;

  const int n4 = (int)(nqk / 4);
  cvt_f16_kernel<<<dim3((n4 + 255) / 256), dim3(256), 0, stream>>>(q, qh, n4);
  cvt_f16_kernel<<<dim3((n4 + 255) / 256), dim3(256), 0, stream>>>(k, kh, n4);
  vtrans_kernel<<<dim3(BATCH * (SEQ / 64)), dim3(256), 0, stream>>>(v, vt);
  attn_kernel<<<dim3(BATCH * (SEQ / 16)), dim3(256), 0, stream>>>(qh, kh, vt, mask, out, attn);
}

// Round 9
// 642.487 us; speedup vs baseline: 1.5113x; 1.5113x over previous
//
#include <hip/hip_runtime.h>
#include <stdint.h>
#include <stddef.h>

// ScaledDotProductAttention: B=64, Lq=Lk=2048, D=64, fp32 in/out.
// out tuple = (output [64][2048][64], attn [64][2048][2048]) concat in d_out.
// R9: ALL global memory instructions are contiguous wave-level runs:
//  - K tile (16k x 64d fp16 = 2KB contiguous) -> regs -> per-wave LDS (144B rows)
//  - V tile (2KB contiguous, native layout)   -> regs -> per-wave LDS transposed (40B rows)
//  - mask / attn: 64-col chunks via per-wave LDS bounce, 4x 1KB instrs (4 rows each)
// MFMA fragments read from LDS. NO barriers in main loops (per-wave LDS regions).
// Softmax/PH/merge/O-reduce identical to R8. XCD remap: batch-contiguous per XCD.

typedef __attribute__((ext_vector_type(4))) float f32x4;
typedef __fp16 f16x2 __attribute__((ext_vector_type(2)));
typedef __fp16 f16x4 __attribute__((ext_vector_type(4)));
typedef __fp16 f16x8 __attribute__((ext_vector_type(8)));

static constexpr int BATCH = 64;
static constexpr int SEQ   = 2048;
static constexpr int HD    = 64;
static constexpr float NEGH = -60000.0f;  // "-inf" that survives fp16

// per-wave LDS byte offsets (within 14080B region)
//  K slots:   0 + s*2304   (16 rows x 144B, s=0,1)
//  VT slots:  4608 + s*2560 (64 d-rows x 40B, s=0,1)
//  M/A buf:   9728 (16 q-rows x 272B)

// ---------------- pre-pass: fp32 -> fp16 flat convert ----------------
__global__ void cvt_f16_kernel(const float* __restrict__ in,
                               __fp16* __restrict__ out, int n4) {
  int i = blockIdx.x * blockDim.x + threadIdx.x;
  if (i >= n4) return;
  f32x4 v = *(const f32x4*)(in + (size_t)i * 4);
  f16x4 o;
  o[0] = (__fp16)v[0]; o[1] = (__fp16)v[1];
  o[2] = (__fp16)v[2]; o[3] = (__fp16)v[3];
  *(f16x4*)(out + (size_t)i * 4) = o;
}

// ---------------- main fused attention ----------------
__global__ __launch_bounds__(256, 2) void attn_kernel(
    const __fp16* __restrict__ qh,
    const __fp16* __restrict__ kh,
    const __fp16* __restrict__ vh,
    const float* __restrict__ mask,
    float* __restrict__ out,
    float* __restrict__ attn) {
  __shared__ float s_red[4][1088];           // O partials [wave][d*17+q]
  __shared__ float stat_m[4][16];
  __shared__ float stat_l[4][16];
  __shared__ __align__(16) char wbuf[4][14080];

  const int tid  = threadIdx.x;
  const int w    = tid >> 6;
  const int lane = tid & 63;
  const int l15  = lane & 15;
  const int g    = lane >> 4;
  const int g4   = g << 2;
  const int g8   = g << 3;
  const int krow = lane >> 3;        // staging row 0..7
  const int kc16 = (lane & 7) * 16;  // staging byte col

  // XCD remap: XCD x handles batches 8x..8x+7 exclusively (L2 residency)
  const int bid = blockIdx.x;
  const int xcd = bid & 7;
  const int r   = bid >> 3;
  const int b   = xcd * 8 + (r >> 7);
  const int q0  = (r & 127) << 4;
  const int wk0 = w << 9;

  char* wb = wbuf[w];

  // Q = B operand (col=l15 -> q-row, k'=g*8+j -> head-dim)
  const __fp16* qptr = qh + ((size_t)(b * SEQ + q0 + l15)) * HD;
  const f16x8 qb0 = *(const f16x8*)(qptr + g8);
  const f16x8 qb1 = *(const f16x8*)(qptr + 32 + g8);

  const __fp16* kstrip = kh + ((size_t)(b * SEQ) + wk0) * HD;
  const __fp16* vstrip = vh + ((size_t)(b * SEQ) + wk0) * HD;
  const float*  mbase  = mask + ((size_t)(b * SEQ + q0)) * SEQ + wk0;
  float*        abase  = attn + ((size_t)(b * SEQ + q0)) * SEQ + wk0;

  // 32 named logit fragments
  f16x4 PH0,  PH1,  PH2,  PH3,  PH4,  PH5,  PH6,  PH7;
  f16x4 PH8,  PH9,  PH10, PH11, PH12, PH13, PH14, PH15;
  f16x4 PH16, PH17, PH18, PH19, PH20, PH21, PH22, PH23;
  f16x4 PH24, PH25, PH26, PH27, PH28, PH29, PH30, PH31;

  f16x8 KA0, KB0, KA1, KB1;                  // K staging reg sets
  f32x4 MA0, MA1, MA2, MA3, MB0, MB1, MB2, MB3;  // mask staging sets
  float m = -3.0e38f;

#define ISSUE_K(t, KA, KB)                                                   \
  KA = *(const f16x8*)(kstrip + (size_t)(t) * 1024 + lane * 8);              \
  KB = *(const f16x8*)(kstrip + (size_t)(t) * 1024 + 512 + lane * 8);

#define WRITE_K(s, KA, KB)                                                   \
  *(f16x8*)(wb + (s) * 2304 + krow * 144 + kc16) = KA;                       \
  *(f16x8*)(wb + (s) * 2304 + (8 + krow) * 144 + kc16) = KB;

#define ISSUE_M(c, M0, M1, M2, M3)                                           \
  M0 = *(const f32x4*)(mbase + (size_t)(0 * 4 + g) * SEQ + (c) * 64 + l15 * 4); \
  M1 = *(const f32x4*)(mbase + (size_t)(1 * 4 + g) * SEQ + (c) * 64 + l15 * 4); \
  M2 = *(const f32x4*)(mbase + (size_t)(2 * 4 + g) * SEQ + (c) * 64 + l15 * 4); \
  M3 = *(const f32x4*)(mbase + (size_t)(3 * 4 + g) * SEQ + (c) * 64 + l15 * 4);

#define WRITE_M(M0, M1, M2, M3)                                              \
  *(f32x4*)(wb + 9728 + (0 * 4 + g) * 272 + l15 * 16) = M0;                  \
  *(f32x4*)(wb + 9728 + (1 * 4 + g) * 272 + l15 * 16) = M1;                  \
  *(f32x4*)(wb + 9728 + (2 * 4 + g) * 272 + l15 * 16) = M2;                  \
  *(f32x4*)(wb + 9728 + (3 * 4 + g) * 272 + l15 * 16) = M3;

#define ATILE(t, s, PH)                                                      \
  {                                                                          \
    const f16x8 fa = *(const f16x8*)(wb + (s) * 2304 + l15 * 144 + g * 16);  \
    const f16x8 fb = *(const f16x8*)(wb + (s) * 2304 + l15 * 144 + 64 + g * 16); \
    f32x4 acc = {0.f, 0.f, 0.f, 0.f};                                        \
    acc = __builtin_amdgcn_mfma_f32_16x16x32_f16(fa, qb0, acc, 0, 0, 0);     \
    acc = __builtin_amdgcn_mfma_f32_16x16x32_f16(fb, qb1, acc, 0, 0, 0);     \
    const f32x4 mv = *(const f32x4*)(wb + 9728 + l15 * 272 + ((t) & 3) * 64 + g * 16); \
    float s0 = (mv[0] < 0.f) ? NEGH : fmaf(acc[0], 0.125f, mv[0]);           \
    float s1 = (mv[1] < 0.f) ? NEGH : fmaf(acc[1], 0.125f, mv[1]);           \
    float s2 = (mv[2] < 0.f) ? NEGH : fmaf(acc[2], 0.125f, mv[2]);           \
    float s3 = (mv[3] < 0.f) ? NEGH : fmaf(acc[3], 0.125f, mv[3]);           \
    m = fmaxf(m, fmaxf(fmaxf(s0, s1), fmaxf(s2, s3)));                       \
    f16x2 lo_ = __builtin_amdgcn_cvt_pkrtz(s0, s1);                          \
    f16x2 hi_ = __builtin_amdgcn_cvt_pkrtz(s2, s3);                          \
    PH = (f16x4){lo_[0], lo_[1], hi_[0], hi_[1]};                            \
  }

#define AT0(t, PH)  WRITE_K(0, KA0, KB0) ISSUE_K((t) + 2, KA0, KB0) ATILE(t, 0, PH)
#define AT1(t, PH)  WRITE_K(1, KA1, KB1) ISSUE_K((t) + 2, KA1, KB1) ATILE(t, 1, PH)
#define AT0L(t, PH) WRITE_K(0, KA0, KB0) ATILE(t, 0, PH)
#define AT1L(t, PH) WRITE_K(1, KA1, KB1) ATILE(t, 1, PH)

  // ---- Phase A ----
  ISSUE_K(0, KA0, KB0)
  ISSUE_K(1, KA1, KB1)
  ISSUE_M(0, MA0, MA1, MA2, MA3)

  WRITE_M(MA0, MA1, MA2, MA3) ISSUE_M(1, MB0, MB1, MB2, MB3)
  AT0(0, PH0)  AT1(1, PH1)  AT0(2, PH2)  AT1(3, PH3)
  WRITE_M(MB0, MB1, MB2, MB3) ISSUE_M(2, MA0, MA1, MA2, MA3)
  AT0(4, PH4)  AT1(5, PH5)  AT0(6, PH6)  AT1(7, PH7)
  WRITE_M(MA0, MA1, MA2, MA3) ISSUE_M(3, MB0, MB1, MB2, MB3)
  AT0(8, PH8)  AT1(9, PH9)  AT0(10, PH10) AT1(11, PH11)
  WRITE_M(MB0, MB1, MB2, MB3) ISSUE_M(4, MA0, MA1, MA2, MA3)
  AT0(12, PH12) AT1(13, PH13) AT0(14, PH14) AT1(15, PH15)
  WRITE_M(MA0, MA1, MA2, MA3) ISSUE_M(5, MB0, MB1, MB2, MB3)
  AT0(16, PH16) AT1(17, PH17) AT0(18, PH18) AT1(19, PH19)
  WRITE_M(MB0, MB1, MB2, MB3) ISSUE_M(6, MA0, MA1, MA2, MA3)
  AT0(20, PH20) AT1(21, PH21) AT0(22, PH22) AT1(23, PH23)
  WRITE_M(MA0, MA1, MA2, MA3) ISSUE_M(7, MB0, MB1, MB2, MB3)
  AT0(24, PH24) AT1(25, PH25) AT0(26, PH26) AT1(27, PH27)
  WRITE_M(MB0, MB1, MB2, MB3)
  AT0(28, PH28) AT1(29, PH29) AT0L(30, PH30) AT1L(31, PH31)

#undef AT0
#undef AT1
#undef AT0L
#undef AT1L
#undef ATILE
#undef ISSUE_K
#undef WRITE_K
#undef ISSUE_M
#undef WRITE_M

  // row max across the 4 g-groups holding the same q-row
  m = fmaxf(m, __shfl_xor(m, 16));
  m = fmaxf(m, __shfl_xor(m, 32));

  // ---- Phase A2: e = exp(s - m), sum, repack e over s ----
  float lw = 0.f;
#define A2_STEP(PH)                                                          \
  {                                                                          \
    float e0 = __expf((float)PH[0] - m);                                     \
    float e1 = __expf((float)PH[1] - m);                                     \
    float e2 = __expf((float)PH[2] - m);                                     \
    float e3 = __expf((float)PH[3] - m);                                     \
    lw += (e0 + e1) + (e2 + e3);                                             \
    f16x2 lo_ = __builtin_amdgcn_cvt_pkrtz(e0, e1);                          \
    f16x2 hi_ = __builtin_amdgcn_cvt_pkrtz(e2, e3);                          \
    PH = (f16x4){lo_[0], lo_[1], hi_[0], hi_[1]};                            \
  }
  A2_STEP(PH0)  A2_STEP(PH1)  A2_STEP(PH2)  A2_STEP(PH3)
  A2_STEP(PH4)  A2_STEP(PH5)  A2_STEP(PH6)  A2_STEP(PH7)
  A2_STEP(PH8)  A2_STEP(PH9)  A2_STEP(PH10) A2_STEP(PH11)
  A2_STEP(PH12) A2_STEP(PH13) A2_STEP(PH14) A2_STEP(PH15)
  A2_STEP(PH16) A2_STEP(PH17) A2_STEP(PH18) A2_STEP(PH19)
  A2_STEP(PH20) A2_STEP(PH21) A2_STEP(PH22) A2_STEP(PH23)
  A2_STEP(PH24) A2_STEP(PH25) A2_STEP(PH26) A2_STEP(PH27)
  A2_STEP(PH28) A2_STEP(PH29) A2_STEP(PH30) A2_STEP(PH31)
#undef A2_STEP

  lw += __shfl_xor(lw, 16);
  lw += __shfl_xor(lw, 32);

  if (lane < 16) { stat_m[w][lane] = m; stat_l[w][lane] = lw; }
  __syncthreads();

  float mg = -3.0e38f;
#pragma unroll
  for (int ww = 0; ww < 4; ++ww) mg = fmaxf(mg, stat_m[ww][l15]);
  float lg = 0.f;
#pragma unroll
  for (int ww = 0; ww < 4; ++ww) lg += stat_l[ww][l15] * __expf(stat_m[ww][l15] - mg);
  const float scale = __expf(m - mg) / lg;
  const __fp16 hs = (__fp16)scale;
  const f16x4 sc4 = {hs, hs, hs, hs};

  // ---- Phase B ----
  f32x4 oacc0 = {0.f, 0.f, 0.f, 0.f};
  f32x4 oacc1 = {0.f, 0.f, 0.f, 0.f};
  f32x4 oacc2 = {0.f, 0.f, 0.f, 0.f};
  f32x4 oacc3 = {0.f, 0.f, 0.f, 0.f};

  f16x8 VA0, VB0, VA1, VB1;

#define ISSUE_V(t, VA, VB)                                                   \
  VA = *(const f16x8*)(vstrip + (size_t)(t) * 1024 + lane * 8);              \
  VB = *(const f16x8*)(vstrip + (size_t)(t) * 1024 + 512 + lane * 8);

#define WRITE_VT(s, VA, VB)                                                  \
  {                                                                          \
    char* p_ = wb + 4608 + (s) * 2560 + ((lane & 7) * 8) * 40 + krow * 2;    \
    *(__fp16*)(p_ + 0 * 40) = VA[0]; *(__fp16*)(p_ + 1 * 40) = VA[1];        \
    *(__fp16*)(p_ + 2 * 40) = VA[2]; *(__fp16*)(p_ + 3 * 40) = VA[3];        \
    *(__fp16*)(p_ + 4 * 40) = VA[4]; *(__fp16*)(p_ + 5 * 40) = VA[5];        \
    *(__fp16*)(p_ + 6 * 40) = VA[6]; *(__fp16*)(p_ + 7 * 40) = VA[7];        \
    char* q_ = p_ + 16;                                                      \
    *(__fp16*)(q_ + 0 * 40) = VB[0]; *(__fp16*)(q_ + 1 * 40) = VB[1];        \
    *(__fp16*)(q_ + 2 * 40) = VB[2]; *(__fp16*)(q_ + 3 * 40) = VB[3];        \
    *(__fp16*)(q_ + 4 * 40) = VB[4]; *(__fp16*)(q_ + 5 * 40) = VB[5];        \
    *(__fp16*)(q_ + 6 * 40) = VB[6]; *(__fp16*)(q_ + 7 * 40) = VB[7];        \
  }

#define BTILE(t, s, PH)                                                      \
  {                                                                          \
    const f16x4 pf = PH * sc4;                                               \
    f32x4 st;                                                                \
    st[0] = (float)pf[0]; st[1] = (float)pf[1];                              \
    st[2] = (float)pf[2]; st[3] = (float)pf[3];                              \
    *(f32x4*)(wb + 9728 + l15 * 272 + ((t) & 3) * 64 + g * 16) = st;         \
    const char* vf_ = wb + 4608 + (s) * 2560 + l15 * 40 + g * 8;             \
    const f16x4 V0_ = *(const f16x4*)(vf_ + 0 * 640);                        \
    const f16x4 V1_ = *(const f16x4*)(vf_ + 1 * 640);                        \
    const f16x4 V2_ = *(const f16x4*)(vf_ + 2 * 640);                        \
    const f16x4 V3_ = *(const f16x4*)(vf_ + 3 * 640);                        \
    oacc0 = __builtin_amdgcn_mfma_f32_16x16x16f16(V0_, pf, oacc0, 0, 0, 0);  \
    oacc1 = __builtin_amdgcn_mfma_f32_16x16x16f16(V1_, pf, oacc1, 0, 0, 0);  \
    oacc2 = __builtin_amdgcn_mfma_f32_16x16x16f16(V2_, pf, oacc2, 0, 0, 0);  \
    oacc3 = __builtin_amdgcn_mfma_f32_16x16x16f16(V3_, pf, oacc3, 0, 0, 0);  \
  }

#define STORE_A(c)                                                           \
  *(f32x4*)(abase + (size_t)(0 * 4 + g) * SEQ + (c) * 64 + l15 * 4) =        \
      *(const f32x4*)(wb + 9728 + (0 * 4 + g) * 272 + l15 * 16);             \
  *(f32x4*)(abase + (size_t)(1 * 4 + g) * SEQ + (c) * 64 + l15 * 4) =        \
      *(const f32x4*)(wb + 9728 + (1 * 4 + g) * 272 + l15 * 16);             \
  *(f32x4*)(abase + (size_t)(2 * 4 + g) * SEQ + (c) * 64 + l15 * 4) =        \
      *(const f32x4*)(wb + 9728 + (2 * 4 + g) * 272 + l15 * 16);             \
  *(f32x4*)(abase + (size_t)(3 * 4 + g) * SEQ + (c) * 64 + l15 * 4) =        \
      *(const f32x4*)(wb + 9728 + (3 * 4 + g) * 272 + l15 * 16);

#define BT0(t, PH)  WRITE_VT(0, VA0, VB0) ISSUE_V((t) + 2, VA0, VB0) BTILE(t, 0, PH)
#define BT1(t, PH)  WRITE_VT(1, VA1, VB1) ISSUE_V((t) + 2, VA1, VB1) BTILE(t, 1, PH)
#define BT0L(t, PH) WRITE_VT(0, VA0, VB0) BTILE(t, 0, PH)
#define BT1L(t, PH) WRITE_VT(1, VA1, VB1) BTILE(t, 1, PH)

  ISSUE_V(0, VA0, VB0)
  ISSUE_V(1, VA1, VB1)

  BT0(0, PH0)   BT1(1, PH1)   BT0(2, PH2)   BT1(3, PH3)   STORE_A(0)
  BT0(4, PH4)   BT1(5, PH5)   BT0(6, PH6)   BT1(7, PH7)   STORE_A(1)
  BT0(8, PH8)   BT1(9, PH9)   BT0(10, PH10) BT1(11, PH11) STORE_A(2)
  BT0(12, PH12) BT1(13, PH13) BT0(14, PH14) BT1(15, PH15) STORE_A(3)
  BT0(16, PH16) BT1(17, PH17) BT0(18, PH18) BT1(19, PH19) STORE_A(4)
  BT0(20, PH20) BT1(21, PH21) BT0(22, PH22) BT1(23, PH23) STORE_A(5)
  BT0(24, PH24) BT1(25, PH25) BT0(26, PH26) BT1(27, PH27) STORE_A(6)
  BT0(28, PH28) BT1(29, PH29) BT0L(30, PH30) BT1L(31, PH31) STORE_A(7)

#undef BT0
#undef BT1
#undef BT0L
#undef BT1L
#undef BTILE
#undef WRITE_VT
#undef ISSUE_V
#undef STORE_A

  // ---- cross-wave partial-O reduction ----
#pragma unroll
  for (int rr = 0; rr < 4; ++rr) {
    s_red[w][(0 * 16 + g4 + rr) * 17 + l15] = oacc0[rr];
    s_red[w][(1 * 16 + g4 + rr) * 17 + l15] = oacc1[rr];
    s_red[w][(2 * 16 + g4 + rr) * 17 + l15] = oacc2[rr];
    s_red[w][(3 * 16 + g4 + rr) * 17 + l15] = oacc3[rr];
  }
  __syncthreads();

#pragma unroll
  for (int ii = 0; ii < 4; ++ii) {
    const int i = tid + ii * 256;     // i in [0,1024): q = i>>6, d = i&63
    const int q = i >> 6;
    const int d = i & 63;
    const int o = d * 17 + q;
    float s = s_red[0][o] + s_red[1][o] + s_red[2][o] + s_red[3][o];
    out[((size_t)(b * SEQ + q0 + q)) * HD + d] = s;
  }
}

extern "C" void kernel_launch(void* const* d_in, const int* in_sizes, int n_in,
                              void* d_out, int out_size, void* d_ws, size_t ws_size,
                              hipStream_t stream) {
  const float* q    = (const float*)d_in[0];
  const float* k    = (const float*)d_in[1];
  const float* v    = (const float*)d_in[2];
  const float* mask = (const float*)d_in[3];

  float* out  = (float*)d_out;
  float* attn = out + (size_t)BATCH * SEQ * HD;  // tuple: (output, attn)

  const size_t nqk = (size_t)BATCH * SEQ * HD;
  __fp16* qh = (__fp16*)d_ws;
  __fp16* kh = qh + nqk;
  __fp16* vhf = kh + nqk;

  const int n4 = (int)(nqk / 4);
  cvt_f16_kernel<<<dim3((n4 + 255) / 256), dim3(256), 0, stream>>>(q, qh, n4);
  cvt_f16_kernel<<<dim3((n4 + 255) / 256), dim3(256), 0, stream>>>(k, kh, n4);
  cvt_f16_kernel<<<dim3((n4 + 255) / 256), dim3(256), 0, stream>>>(v, vhf, n4);
  attn_kernel<<<dim3(BATCH * (SEQ / 16)), dim3(256), 0, stream>>>(qh, kh, vhf, mask, out, attn);
}